// Round 2
// baseline (491.803 us; speedup 1.0000x reference)
//
#include <hip/hip_runtime.h>

typedef unsigned short u16;
typedef __attribute__((ext_vector_type(8))) short short8;
typedef __attribute__((ext_vector_type(4))) float floatx4;

#define MFMA16(A, B, C) __builtin_amdgcn_mfma_f32_16x16x32_bf16((A), (B), (C), 0, 0, 0)

// ws layout (u16 element offsets)
#define OF_SPEC  64                       // canonical bf16 spec [204800]
#define OF_SMALL (OF_SPEC + 204800)       // 8 x 256: W1,b1,b2,bq,bk,bv,bo,bp (bf16)
#define OF_W     (OF_SMALL + 2048)        // 5 x 65536: swizzled W2,Wq,Wk,Wv,Wo
#define OF_WP    (OF_W + 5 * 65536)       // 524288: swizzled Wp
// total = 1,058,880 u16 = 2,117,760 bytes

static __device__ __forceinline__ float bf2f(u16 u) {
  union { unsigned int i; float f; } z; z.i = ((unsigned int)u) << 16; return z.f;
}
static __device__ __forceinline__ u16 f2bf(float f) {
  union { float f; unsigned int i; } z; z.f = f;
  unsigned int x = z.i + 0x7fffu + ((z.i >> 16) & 1u);  // RNE
  return (u16)(x >> 16);
}
static __device__ __forceinline__ void ld8f(const u16* p, float* o) {
  union { short8 v; u16 u[8]; } t;
  t.v = *(const short8*)p;
#pragma unroll
  for (int j = 0; j < 8; ++j) o[j] = bf2f(t.u[j]);
}

// Decide whether inputs are bf16 (flag=0) or f32 (flag=1) by decoding the first
// 256 u16 of spec as bf16. Real bf16 N(0,1) data never has exponent >= 137
// (|x| > ~1e3); f32-as-u16 garbage hits that ~23% of the time.
__global__ void detect_kernel(const u16* __restrict__ spec_u16, int* __restrict__ flag) {
  const int lane = threadIdx.x;
  int bad = 0;
#pragma unroll
  for (int j = 0; j < 4; ++j) {
    u16 v = spec_u16[lane * 4 + j];
    int e = (v >> 7) & 0xFF;
    bad += (e >= 137);
  }
  unsigned long long m = __ballot(bad > 0);
  if (lane == 0) *flag = (__popcll(m) >= 4) ? 1 : 0;
}

#define CV(src, idx) (flag ? f2bf(((const float*)(src))[idx]) : ((const u16*)(src))[idx])

// Convert spec + small tensors to canonical bf16, and repack each weight
// W[K][256] into fragment-major order so one MFMA B-fragment (8 consecutive k
// for one n) is a contiguous 16B chunk: dst[(k>>3)*2048 + n*8 + (k&7)] = W[k][n]
__global__ void prep_kernel(
    const int* __restrict__ flagp,
    const void* spec, const void* W1, const void* b1, const void* W2, const void* b2,
    const void* Wq, const void* bq, const void* Wk, const void* bk, const void* Wv,
    const void* bv, const void* Wo, const void* bo, const void* Wp, const void* bp,
    u16* __restrict__ ws) {
  const int flag = *flagp;
  int i = blockIdx.x * 256 + threadIdx.x;
  if (i < 204800) { ws[OF_SPEC + i] = CV(spec, i); return; }
  int j = i - 204800;
  if (j < 2048) {
    const void* srcs[8] = {W1, b1, b2, bq, bk, bv, bo, bp};
    ws[OF_SMALL + j] = CV(srcs[j >> 8], j & 255);
    return;
  }
  j -= 2048;
  if (j < 327680) {
    const void* srcs[5] = {W2, Wq, Wk, Wv, Wo};
    const int a = j >> 16, idx = j & 65535;
    const int k = idx >> 8, n = idx & 255;
    ws[OF_W + a * 65536 + (k >> 3) * 2048 + n * 8 + (k & 7)] = CV(srcs[a], idx);
    return;
  }
  j -= 327680;
  {
    const int k = j >> 8, n = j & 255;
    ws[OF_WP + (k >> 3) * 2048 + n * 8 + (k & 7)] = CV(Wp, j);
  }
}

// One block = 64 tokens = 8 windows. Fully fused:
//   e = relu(spec*W1+b1)@W2+b2 -> q,k,v (2 heads/chunk) -> window attention
//   -> partial-K Wo accumulate -> patch projection [8 x 2048]@Wp -> out.
__global__ __launch_bounds__(256, 2) void fused_kernel(
    const u16* __restrict__ csp,   // canonical bf16 spec
    const u16* __restrict__ csm,   // W1,b1,b2,bq,bk,bv,bo,bp (8 x 256)
    const u16* __restrict__ sW2, const u16* __restrict__ sWq,
    const u16* __restrict__ sWk, const u16* __restrict__ sWv,
    const u16* __restrict__ sWo, const u16* __restrict__ sWp,
    const int* __restrict__ flagp,
    void* __restrict__ out)
{
  __shared__ u16 lds[32768];          // exactly 64 KB
  u16* eb = lds;                      // [64][256] e tile; later oo (= patch A [8][2048])
  u16* qb = lds + 16384;              // [64][64] per-chunk q
  u16* kb = qb + 4096;                // [64][64] per-chunk k
  u16* vb = kb + 4096;                // [64][64] per-chunk v
  u16* ob = vb + 4096;                // [64][64] per-chunk attention out

  const u16* cW1 = csm;
  const u16* cb1 = csm + 256;
  const u16* cb2 = csm + 512;
  const u16* cbq = csm + 768;
  const u16* cbk = csm + 1024;
  const u16* cbv = csm + 1280;
  const u16* cbo = csm + 1536;
  const u16* cbp = csm + 1792;

  const int flag = *flagp;
  const int tid = threadIdx.x;
  const int wave = tid >> 6, lane = tid & 63;
  const int l15 = lane & 15, quad = lane >> 4;
  const int tile0 = blockIdx.x * 64;

  float sv[4];
#pragma unroll
  for (int mi = 0; mi < 4; ++mi) sv[mi] = bf2f(csp[tile0 + mi * 16 + l15]);

  // ---------------- phase 0: e tile (wave computes cols [wave*64, +64)) ----------
  {
    const int nbase = wave * 64;
    floatx4 acc[4][4];
#pragma unroll
    for (int mi = 0; mi < 4; ++mi)
#pragma unroll
      for (int ni = 0; ni < 4; ++ni) acc[mi][ni] = (floatx4){0.f, 0.f, 0.f, 0.f};
    for (int kc = 0; kc < 8; ++kc) {
      const int k0 = kc * 32 + quad * 8;
      float w1f[8], b1f[8];
      ld8f(cW1 + k0, w1f);
      ld8f(cb1 + k0, b1f);
      short8 afr[4];
#pragma unroll
      for (int mi = 0; mi < 4; ++mi) {
        union { short8 s; u16 u[8]; } av;
#pragma unroll
        for (int j = 0; j < 8; ++j) {
          float x = fmaf(sv[mi], w1f[j], b1f[j]);
          av.u[j] = f2bf(x > 0.f ? x : 0.f);
        }
        afr[mi] = av.s;
      }
#pragma unroll
      for (int ni = 0; ni < 4; ++ni) {
        short8 bfr = *(const short8*)(sW2 + ((kc * 4 + quad) * 256 + nbase + ni * 16 + l15) * 8);
#pragma unroll
        for (int mi = 0; mi < 4; ++mi) acc[mi][ni] = MFMA16(afr[mi], bfr, acc[mi][ni]);
      }
    }
#pragma unroll
    for (int ni = 0; ni < 4; ++ni) {
      const int n = nbase + ni * 16 + l15;
      const float bb = bf2f(cb2[n]);
#pragma unroll
      for (int mi = 0; mi < 4; ++mi)
#pragma unroll
        for (int r = 0; r < 4; ++r)
          eb[(mi * 16 + quad * 4 + r) * 256 + n] = f2bf(acc[mi][ni][r] + bb);
    }
  }
  __syncthreads();

  floatx4 ooacc[4][4];
#pragma unroll
  for (int mi = 0; mi < 4; ++mi)
#pragma unroll
    for (int ni = 0; ni < 4; ++ni) ooacc[mi][ni] = (floatx4){0.f, 0.f, 0.f, 0.f};

  // ---------------- 4 chunks of 2 heads (64 cols) each ---------------------------
  for (int c = 0; c < 4; ++c) {
    const int nb_c = c * 64;
    const int col = nb_c + wave * 16 + l15;  // global qkv col this lane produces

    // q,k,v GEMMs: each wave produces a 16-col slice, shared A-fragments
    {
      floatx4 facc[3][4];
#pragma unroll
      for (int x = 0; x < 3; ++x)
#pragma unroll
        for (int mi = 0; mi < 4; ++mi) facc[x][mi] = (floatx4){0.f, 0.f, 0.f, 0.f};
      for (int kc = 0; kc < 8; ++kc) {
        short8 afr[4];
#pragma unroll
        for (int mi = 0; mi < 4; ++mi)
          afr[mi] = *(const short8*)(eb + (mi * 16 + l15) * 256 + kc * 32 + quad * 8);
        const int wo = ((kc * 4 + quad) * 256 + col) * 8;
        short8 bq8 = *(const short8*)(sWq + wo);
        short8 bk8 = *(const short8*)(sWk + wo);
        short8 bv8 = *(const short8*)(sWv + wo);
#pragma unroll
        for (int mi = 0; mi < 4; ++mi) {
          facc[0][mi] = MFMA16(afr[mi], bq8, facc[0][mi]);
          facc[1][mi] = MFMA16(afr[mi], bk8, facc[1][mi]);
          facc[2][mi] = MFMA16(afr[mi], bv8, facc[2][mi]);
        }
      }
      const int lc = wave * 16 + l15;
      const float bqv = bf2f(cbq[col]), bkv = bf2f(cbk[col]), bvv = bf2f(cbv[col]);
#pragma unroll
      for (int mi = 0; mi < 4; ++mi)
#pragma unroll
        for (int r = 0; r < 4; ++r) {
          const int rr = (mi * 16 + quad * 4 + r) * 64 + lc;
          qb[rr] = f2bf(facc[0][mi][r] + bqv);
          kb[rr] = f2bf(facc[1][mi][r] + bkv);
          vb[rr] = f2bf(facc[2][mi][r] + bvv);
        }
    }
    __syncthreads();

    // attention: 16 window-heads x 16 threads (2 threads per q-row, 16 dims each)
    {
      const int wh = tid >> 4, win = wh >> 1, hl = wh & 1;
      const int sub = tid & 15, row = sub >> 1, half = sub & 1;
      const u16* qr = qb + (win * 8 + row) * 64 + hl * 32;
      float qf[32];
      ld8f(qr, qf); ld8f(qr + 8, qf + 8); ld8f(qr + 16, qf + 16); ld8f(qr + 24, qf + 24);
      float s[8];
#pragma unroll
      for (int kk = 0; kk < 8; ++kk) {
        const u16* kr = kb + (win * 8 + kk) * 64 + hl * 32;
        float kf[8], a = 0.f;
        ld8f(kr, kf);
#pragma unroll
        for (int j = 0; j < 8; ++j) a = fmaf(qf[j], kf[j], a);
        ld8f(kr + 8, kf);
#pragma unroll
        for (int j = 0; j < 8; ++j) a = fmaf(qf[8 + j], kf[j], a);
        ld8f(kr + 16, kf);
#pragma unroll
        for (int j = 0; j < 8; ++j) a = fmaf(qf[16 + j], kf[j], a);
        ld8f(kr + 24, kf);
#pragma unroll
        for (int j = 0; j < 8; ++j) a = fmaf(qf[24 + j], kf[j], a);
        s[kk] = a * 0.17677669529663687f;  // 1/sqrt(32)
      }
      float mx = s[0];
#pragma unroll
      for (int kk = 1; kk < 8; ++kk) mx = fmaxf(mx, s[kk]);
      float p[8], sum = 0.f;
#pragma unroll
      for (int kk = 0; kk < 8; ++kk) { p[kk] = __expf(s[kk] - mx); sum += p[kk]; }
      const float inv = 1.f / sum;
      float o[16];
#pragma unroll
      for (int d = 0; d < 16; ++d) o[d] = 0.f;
#pragma unroll
      for (int kk = 0; kk < 8; ++kk) {
        const u16* vr = vb + (win * 8 + kk) * 64 + hl * 32 + half * 16;
        float vf[16];
        ld8f(vr, vf); ld8f(vr + 8, vf + 8);
        const float pk = p[kk] * inv;
#pragma unroll
        for (int d = 0; d < 16; ++d) o[d] = fmaf(pk, vf[d], o[d]);
      }
      u16* orow = ob + (win * 8 + row) * 64 + hl * 32 + half * 16;
#pragma unroll
      for (int d = 0; d < 16; d += 2) {
        unsigned int pk2 = (unsigned int)f2bf(o[d]) | ((unsigned int)f2bf(o[d + 1]) << 16);
        *(unsigned int*)(orow + d) = pk2;
      }
    }
    __syncthreads();

    // partial Wo accumulate over this chunk's K-slice [nb_c, nb_c+64)
#pragma unroll
    for (int kc = 0; kc < 2; ++kc) {
      short8 afr[4];
#pragma unroll
      for (int mi = 0; mi < 4; ++mi)
        afr[mi] = *(const short8*)(ob + (mi * 16 + l15) * 64 + kc * 32 + quad * 8);
#pragma unroll
      for (int ni = 0; ni < 4; ++ni) {
        const int n = wave * 64 + ni * 16 + l15;
        const int g = c * 8 + kc * 4 + quad;
        short8 bfr = *(const short8*)(sWo + (g * 256 + n) * 8);
#pragma unroll
        for (int mi = 0; mi < 4; ++mi) ooacc[mi][ni] = MFMA16(afr[mi], bfr, ooacc[mi][ni]);
      }
    }
    // no barrier needed: next chunk's qkv writes (qb/kb/vb) are ordered vs this
    // chunk's attention reads by the post-qkv barrier, and next chunk's ob writes
    // are ordered vs this chunk's Wo reads by that same barrier.
  }

  // oo (+bo) -> eb. Row-major [64 tok][256] == patch A [8 windows][2048].
#pragma unroll
  for (int ni = 0; ni < 4; ++ni) {
    const int n = wave * 64 + ni * 16 + l15;
    const float bb = bf2f(cbo[n]);
#pragma unroll
    for (int mi = 0; mi < 4; ++mi)
#pragma unroll
      for (int r = 0; r < 4; ++r)
        eb[(mi * 16 + quad * 4 + r) * 256 + n] = f2bf(ooacc[mi][ni][r] + bb);
  }
  __syncthreads();

  // ---------------- patch projection: [8 x 2048] @ Wp + bp -----------------------
  // M=16 MFMA tile; A rows 8..15 read finite bf16 data from qb/kb/vb/ob (still
  // inside lds[32768]) and are discarded on store.
  {
    floatx4 pacc[4];
#pragma unroll
    for (int ni = 0; ni < 4; ++ni) pacc[ni] = (floatx4){0.f, 0.f, 0.f, 0.f};
#pragma unroll 4
    for (int kc = 0; kc < 64; ++kc) {
      short8 afr = *(const short8*)(eb + l15 * 2048 + kc * 32 + quad * 8);
#pragma unroll
      for (int ni = 0; ni < 4; ++ni) {
        const int n = wave * 64 + ni * 16 + l15;
        short8 bfr = *(const short8*)(sWp + ((kc * 4 + quad) * 256 + n) * 8);
        pacc[ni] = MFMA16(afr, bfr, pacc[ni]);
      }
    }
    if (quad < 2) {
      if (flag) {
        float* po = (float*)out;
#pragma unroll
        for (int ni = 0; ni < 4; ++ni) {
          const int n = wave * 64 + ni * 16 + l15;
          const float bb = bf2f(cbp[n]);
#pragma unroll
          for (int r = 0; r < 4; ++r)
            po[(blockIdx.x * 8 + quad * 4 + r) * 256 + n] = pacc[ni][r] + bb;
        }
      } else {
        u16* po = (u16*)out;
#pragma unroll
        for (int ni = 0; ni < 4; ++ni) {
          const int n = wave * 64 + ni * 16 + l15;
          const float bb = bf2f(cbp[n]);
#pragma unroll
          for (int r = 0; r < 4; ++r)
            po[(blockIdx.x * 8 + quad * 4 + r) * 256 + n] = f2bf(pacc[ni][r] + bb);
        }
      }
    }
  }
}

extern "C" void kernel_launch(void* const* d_in, const int* in_sizes, int n_in,
                              void* d_out, int out_size, void* d_ws, size_t ws_size,
                              hipStream_t stream) {
  (void)in_sizes; (void)n_in; (void)out_size; (void)ws_size;
  int* flag = (int*)d_ws;
  u16* ws = (u16*)d_ws;

  detect_kernel<<<1, 64, 0, stream>>>((const u16*)d_in[0], flag);
  prep_kernel<<<4136, 256, 0, stream>>>(flag,
      d_in[0], d_in[1], d_in[2], d_in[3], d_in[4], d_in[5], d_in[6], d_in[7],
      d_in[8], d_in[9], d_in[10], d_in[11], d_in[12], d_in[13], d_in[14], ws);
  fused_kernel<<<3200, 256, 0, stream>>>(
      ws + OF_SPEC, ws + OF_SMALL,
      ws + OF_W, ws + OF_W + 65536, ws + OF_W + 2 * 65536,
      ws + OF_W + 3 * 65536, ws + OF_W + 4 * 65536, ws + OF_WP,
      flag, d_out);
}

// Round 3
// 440.984 us; speedup vs baseline: 1.1152x; 1.1152x over previous
//
#include <hip/hip_runtime.h>

typedef unsigned short u16;
typedef __attribute__((ext_vector_type(8))) short short8;
typedef __attribute__((ext_vector_type(4))) float floatx4;

#define MFMA16(A, B, C) __builtin_amdgcn_mfma_f32_16x16x32_bf16((A), (B), (C), 0, 0, 0)

// ws layout (u16 element offsets)
#define OF_SPEC  64                       // canonical bf16 spec [204800]
#define OF_SMALL (OF_SPEC + 204800)       // 8 x 256: W1,b1,b2,bq,bk,bv,bo,bp (bf16)
#define OF_W     (OF_SMALL + 2048)        // 5 x 65536: swizzled W2,Wq,Wk,Wv,Wo
#define OF_WP    (OF_W + 5 * 65536)       // 524288: swizzled Wp

static __device__ __forceinline__ float bf2f(u16 u) {
  union { unsigned int i; float f; } z; z.i = ((unsigned int)u) << 16; return z.f;
}
static __device__ __forceinline__ u16 f2bf(float f) {
  union { float f; unsigned int i; } z; z.f = f;
  unsigned int x = z.i + 0x7fffu + ((z.i >> 16) & 1u);  // RNE
  return (u16)(x >> 16);
}
static __device__ __forceinline__ void ld8f(const u16* p, float* o) {
  union { short8 v; u16 u[8]; } t;
  t.v = *(const short8*)p;
#pragma unroll
  for (int j = 0; j < 8; ++j) o[j] = bf2f(t.u[j]);
}

// bf16 (flag=0) vs f32 (flag=1) input detection on first 256 u16 of spec.
__global__ void detect_kernel(const u16* __restrict__ spec_u16, int* __restrict__ flag) {
  const int lane = threadIdx.x;
  int bad = 0;
#pragma unroll
  for (int j = 0; j < 4; ++j) {
    u16 v = spec_u16[lane * 4 + j];
    int e = (v >> 7) & 0xFF;
    bad += (e >= 137);
  }
  unsigned long long m = __ballot(bad > 0);
  if (lane == 0) *flag = (__popcll(m) >= 4) ? 1 : 0;
}

#define CV(src, idx) (flag ? f2bf(((const float*)(src))[idx]) : ((const u16*)(src))[idx])

// Canonicalize to bf16; weights into fragment-major: dst[(k>>3)*2048 + n*8 + (k&7)]
__global__ void prep_kernel(
    const int* __restrict__ flagp,
    const void* spec, const void* W1, const void* b1, const void* W2, const void* b2,
    const void* Wq, const void* bq, const void* Wk, const void* bk, const void* Wv,
    const void* bv, const void* Wo, const void* bo, const void* Wp, const void* bp,
    u16* __restrict__ ws) {
  const int flag = *flagp;
  int i = blockIdx.x * 256 + threadIdx.x;
  if (i < 204800) { ws[OF_SPEC + i] = CV(spec, i); return; }
  int j = i - 204800;
  if (j < 2048) {
    const void* srcs[8] = {W1, b1, b2, bq, bk, bv, bo, bp};
    ws[OF_SMALL + j] = CV(srcs[j >> 8], j & 255);
    return;
  }
  j -= 2048;
  if (j < 327680) {
    const void* srcs[5] = {W2, Wq, Wk, Wv, Wo};
    const int a = j >> 16, idx = j & 65535;
    const int k = idx >> 8, n = idx & 255;
    ws[OF_W + a * 65536 + (k >> 3) * 2048 + n * 8 + (k & 7)] = CV(srcs[a], idx);
    return;
  }
  j -= 327680;
  {
    const int k = j >> 8, n = j & 255;
    ws[OF_WP + (k >> 3) * 2048 + n * 8 + (k & 7)] = CV(Wp, j);
  }
}

// One block = 64 tokens = 8 windows, fully fused. All LDS A-operand tiles are
// stored fragment-major so ds_read_b128 fragment loads are bank-uniform.
__global__ __launch_bounds__(256, 2) void fused_kernel(
    const u16* __restrict__ csp, const u16* __restrict__ csm,
    const u16* __restrict__ sW2, const u16* __restrict__ sWq,
    const u16* __restrict__ sWk, const u16* __restrict__ sWv,
    const u16* __restrict__ sWo, const u16* __restrict__ sWp,
    const int* __restrict__ flagp,
    void* __restrict__ out)
{
  __shared__ u16 lds[32768];          // exactly 64 KB -> 2 blocks/CU
  u16* eA  = lds;                     // 16384: frag-major e A[m<64][k<256]; later patchA
  u16* qb  = lds + 16384;             // 64 x 64, XOR-swizzled cols
  u16* kb  = qb + 4096;
  u16* vb  = kb + 4096;
  u16* obA = vb + 4096;               // 4096: frag-major A[m<64][k<64]

  const u16* cW1 = csm;
  const u16* cb1 = csm + 256;
  const u16* cb2 = csm + 512;
  const u16* cbq = csm + 768;
  const u16* cbk = csm + 1024;
  const u16* cbv = csm + 1280;
  const u16* cbo = csm + 1536;
  const u16* cbp = csm + 1792;

  const int flag = *flagp;
  const int tid = threadIdx.x;
  const int wave = tid >> 6, lane = tid & 63;
  const int l15 = lane & 15, quad = lane >> 4;
  const int tile0 = blockIdx.x * 64;

  float sv[4];
#pragma unroll
  for (int mi = 0; mi < 4; ++mi) sv[mi] = bf2f(csp[tile0 + mi * 16 + l15]);

  // ---------------- phase 0: e tile -> eA fragment-major ----------------
  {
    const int nbase = wave * 64;
    floatx4 acc[4][4];
#pragma unroll
    for (int mi = 0; mi < 4; ++mi)
#pragma unroll
      for (int ni = 0; ni < 4; ++ni) acc[mi][ni] = (floatx4){0.f, 0.f, 0.f, 0.f};
    for (int kc = 0; kc < 8; ++kc) {
      const int k0 = kc * 32 + quad * 8;
      float w1f[8], b1f[8];
      ld8f(cW1 + k0, w1f);
      ld8f(cb1 + k0, b1f);
      short8 afr[4];
#pragma unroll
      for (int mi = 0; mi < 4; ++mi) {
        union { short8 s; u16 u[8]; } av;
#pragma unroll
        for (int j = 0; j < 8; ++j) {
          float x = fmaf(sv[mi], w1f[j], b1f[j]);
          av.u[j] = f2bf(x > 0.f ? x : 0.f);
        }
        afr[mi] = av.s;
      }
#pragma unroll
      for (int ni = 0; ni < 4; ++ni) {
        short8 bfr = *(const short8*)(sW2 + ((kc * 4 + quad) * 256 + nbase + ni * 16 + l15) * 8);
#pragma unroll
        for (int mi = 0; mi < 4; ++mi) acc[mi][ni] = MFMA16(afr[mi], bfr, acc[mi][ni]);
      }
    }
#pragma unroll
    for (int ni = 0; ni < 4; ++ni) {
      const int n = nbase + ni * 16 + l15;
      const float bb = bf2f(cb2[n]);
      const int blk = (n >> 3) * 512 + (n & 7);
#pragma unroll
      for (int mi = 0; mi < 4; ++mi)
#pragma unroll
        for (int r = 0; r < 4; ++r)
          eA[blk + (mi * 16 + quad * 4 + r) * 8] = f2bf(acc[mi][ni][r] + bb);
    }
  }
  __syncthreads();

  floatx4 ooacc[4][4];
#pragma unroll
  for (int mi = 0; mi < 4; ++mi)
#pragma unroll
    for (int ni = 0; ni < 4; ++ni) ooacc[mi][ni] = (floatx4){0.f, 0.f, 0.f, 0.f};

  // ---------------- 4 chunks of 2 heads (64 cols) each ------------------
  for (int c = 0; c < 4; ++c) {
    const int nb_c = c * 64;
    const int col = nb_c + wave * 16 + l15;

    // q,k,v GEMMs
    {
      floatx4 facc[3][4];
#pragma unroll
      for (int x = 0; x < 3; ++x)
#pragma unroll
        for (int mi = 0; mi < 4; ++mi) facc[x][mi] = (floatx4){0.f, 0.f, 0.f, 0.f};
      for (int kc = 0; kc < 8; ++kc) {
        short8 afr[4];
#pragma unroll
        for (int mi = 0; mi < 4; ++mi)
          afr[mi] = *(const short8*)(eA + (kc * 4 + quad) * 512 + (mi * 16 + l15) * 8);
        const int wo = ((kc * 4 + quad) * 256 + col) * 8;
        short8 bq8 = *(const short8*)(sWq + wo);
        short8 bk8 = *(const short8*)(sWk + wo);
        short8 bv8 = *(const short8*)(sWv + wo);
#pragma unroll
        for (int mi = 0; mi < 4; ++mi) {
          facc[0][mi] = MFMA16(afr[mi], bq8, facc[0][mi]);
          facc[1][mi] = MFMA16(afr[mi], bk8, facc[1][mi]);
          facc[2][mi] = MFMA16(afr[mi], bv8, facc[2][mi]);
        }
      }
      const int lc = wave * 16 + l15;
      const float bqv = bf2f(cbq[col]), bkv = bf2f(cbk[col]), bvv = bf2f(cbv[col]);
#pragma unroll
      for (int mi = 0; mi < 4; ++mi)
#pragma unroll
        for (int r = 0; r < 4; ++r) {
          const int tr = mi * 16 + quad * 4 + r;
          const int rr = tr * 64 + ((((lc >> 3) ^ (tr & 7)) << 3) | (lc & 7));
          qb[rr] = f2bf(facc[0][mi][r] + bqv);
          kb[rr] = f2bf(facc[1][mi][r] + bkv);
          vb[rr] = f2bf(facc[2][mi][r] + bvv);
        }
    }
    __syncthreads();

    // attention: 16 window-heads x (8 rows x 2 halves); halves split the
    // 32-dim dot and combine with one shfl_xor.
    {
      const int wh = tid >> 4, win = wh >> 1, hl = wh & 1;
      const int sub = tid & 15, row = sub >> 1, half = sub & 1;
      const int cb0 = hl * 4 + half * 2;   // col8 base of this thread's 16 dims
      const u16* qbase = qb + (win * 8 + row) * 64;
      float qf[16];
      ld8f(qbase + ((cb0 ^ row) << 3), qf);
      ld8f(qbase + (((cb0 + 1) ^ row) << 3), qf + 8);
      float s[8];
#pragma unroll
      for (int kk = 0; kk < 8; ++kk) {
        const u16* kbase = kb + (win * 8 + kk) * 64;
        float kf[8], a = 0.f;
        ld8f(kbase + ((cb0 ^ kk) << 3), kf);
#pragma unroll
        for (int j = 0; j < 8; ++j) a = fmaf(qf[j], kf[j], a);
        ld8f(kbase + (((cb0 + 1) ^ kk) << 3), kf);
#pragma unroll
        for (int j = 0; j < 8; ++j) a = fmaf(qf[8 + j], kf[j], a);
        a += __shfl_xor(a, 1);
        s[kk] = a * 0.17677669529663687f;  // 1/sqrt(32)
      }
      float mx = s[0];
#pragma unroll
      for (int kk = 1; kk < 8; ++kk) mx = fmaxf(mx, s[kk]);
      float p[8], sum = 0.f;
#pragma unroll
      for (int kk = 0; kk < 8; ++kk) { p[kk] = __expf(s[kk] - mx); sum += p[kk]; }
      const float inv = 1.f / sum;
      float o[16];
#pragma unroll
      for (int d = 0; d < 16; ++d) o[d] = 0.f;
#pragma unroll
      for (int kk = 0; kk < 8; ++kk) {
        const u16* vbase = vb + (win * 8 + kk) * 64;
        float vf[16];
        ld8f(vbase + ((cb0 ^ kk) << 3), vf);
        ld8f(vbase + (((cb0 + 1) ^ kk) << 3), vf + 8);
        const float pk = p[kk] * inv;
#pragma unroll
        for (int d = 0; d < 16; ++d) o[d] = fmaf(pk, vf[d], o[d]);
      }
      // write to obA fragment-major: two aligned 16B stores
      const int m = win * 8 + row;
      union { short8 s8; u16 u[8]; } t0, t1;
#pragma unroll
      for (int j = 0; j < 8; ++j) { t0.u[j] = f2bf(o[j]); t1.u[j] = f2bf(o[8 + j]); }
      *(short8*)(obA + cb0 * 512 + m * 8) = t0.s8;
      *(short8*)(obA + (cb0 + 1) * 512 + m * 8) = t1.s8;
    }
    __syncthreads();

    // partial Wo accumulate over this chunk's K-slice
#pragma unroll
    for (int kc = 0; kc < 2; ++kc) {
      short8 afr[4];
#pragma unroll
      for (int mi = 0; mi < 4; ++mi)
        afr[mi] = *(const short8*)(obA + (kc * 4 + quad) * 512 + (mi * 16 + l15) * 8);
#pragma unroll
      for (int ni = 0; ni < 4; ++ni) {
        const int n = wave * 64 + ni * 16 + l15;
        const int g = c * 8 + kc * 4 + quad;
        short8 bfr = *(const short8*)(sWo + (g * 256 + n) * 8);
#pragma unroll
        for (int mi = 0; mi < 4; ++mi) ooacc[mi][ni] = MFMA16(afr[mi], bfr, ooacc[mi][ni]);
      }
    }
  }

  // oo (+bo) -> patchA (reusing eA region), fragment-major over k in [0,2048):
  //   k = p*256 + n, addr = (p*32 + (n>>3))*64 + w*8 + (n&7)
#pragma unroll
  for (int ni = 0; ni < 4; ++ni) {
    const int n = wave * 64 + ni * 16 + l15;
    const float bb = bf2f(cbo[n]);
    const int nb8 = (n >> 3) * 64 + (n & 7);
#pragma unroll
    for (int mi = 0; mi < 4; ++mi)
#pragma unroll
      for (int r = 0; r < 4; ++r) {
        const int tr = mi * 16 + quad * 4 + r;
        eA[(tr >> 3) * 8 + ((tr & 7) * 32) * 64 + nb8] = f2bf(ooacc[mi][ni][r] + bb);
      }
  }
  __syncthreads();

  // ---------------- patch projection: [8 x 2048] @ Wp + bp ----------------
  // A-frag lanes 8..15 broadcast rows 0..7 (same address, free); their output
  // rows are discarded.
  {
    const int w8 = (l15 & 7) * 8;
    floatx4 pacc[4];
#pragma unroll
    for (int ni = 0; ni < 4; ++ni) pacc[ni] = (floatx4){0.f, 0.f, 0.f, 0.f};
#pragma unroll 4
    for (int kc = 0; kc < 64; ++kc) {
      short8 afr = *(const short8*)(eA + (kc * 4 + quad) * 64 + w8);
#pragma unroll
      for (int ni = 0; ni < 4; ++ni) {
        const int n = wave * 64 + ni * 16 + l15;
        short8 bfr = *(const short8*)(sWp + ((kc * 4 + quad) * 256 + n) * 8);
        pacc[ni] = MFMA16(afr, bfr, pacc[ni]);
      }
    }
    if (quad < 2) {
      if (flag) {
        float* po = (float*)out;
#pragma unroll
        for (int ni = 0; ni < 4; ++ni) {
          const int n = wave * 64 + ni * 16 + l15;
          const float bb = bf2f(cbp[n]);
#pragma unroll
          for (int r = 0; r < 4; ++r)
            po[(blockIdx.x * 8 + quad * 4 + r) * 256 + n] = pacc[ni][r] + bb;
        }
      } else {
        u16* po = (u16*)out;
#pragma unroll
        for (int ni = 0; ni < 4; ++ni) {
          const int n = wave * 64 + ni * 16 + l15;
          const float bb = bf2f(cbp[n]);
#pragma unroll
          for (int r = 0; r < 4; ++r)
            po[(blockIdx.x * 8 + quad * 4 + r) * 256 + n] = f2bf(pacc[ni][r] + bb);
        }
      }
    }
  }
}

extern "C" void kernel_launch(void* const* d_in, const int* in_sizes, int n_in,
                              void* d_out, int out_size, void* d_ws, size_t ws_size,
                              hipStream_t stream) {
  (void)in_sizes; (void)n_in; (void)out_size; (void)ws_size;
  int* flag = (int*)d_ws;
  u16* ws = (u16*)d_ws;

  detect_kernel<<<1, 64, 0, stream>>>((const u16*)d_in[0], flag);
  prep_kernel<<<4136, 256, 0, stream>>>(flag,
      d_in[0], d_in[1], d_in[2], d_in[3], d_in[4], d_in[5], d_in[6], d_in[7],
      d_in[8], d_in[9], d_in[10], d_in[11], d_in[12], d_in[13], d_in[14], ws);
  fused_kernel<<<3200, 256, 0, stream>>>(
      ws + OF_SPEC, ws + OF_SMALL,
      ws + OF_W, ws + OF_W + 65536, ws + OF_W + 2 * 65536,
      ws + OF_W + 3 * 65536, ws + OF_W + 4 * 65536, ws + OF_WP,
      flag, d_out);
}